// Round 1
// baseline (1768.121 us; speedup 1.0000x reference)
//
#include <hip/hip_runtime.h>

#define N_NODES 50000
#define N_EDGES 800000
#define DIM 256
#define NG 64
#define EPS_BN 1e-5f

// ============================ BN statistics ============================
__global__ __launch_bounds__(256) void col_stats_kernel(const float* __restrict__ X, int n,
                                                        float* __restrict__ sums, int relu) {
    int c = threadIdx.x;
    float s = 0.f, q = 0.f;
    for (int i = blockIdx.x; i < n; i += gridDim.x) {
        float v = X[(size_t)i * DIM + c];
        if (relu) v = fmaxf(v, 0.f);
        s += v; q += v * v;
    }
    atomicAdd(&sums[c], s);
    atomicAdd(&sums[DIM + c], q);
}

__global__ void finalize_stats_kernel(const float* __restrict__ sums, float* __restrict__ mr, float inv_n) {
    int c = threadIdx.x;
    float m = sums[c] * inv_n;
    float v = sums[DIM + c] * inv_n - m * m;
    mr[c] = m;
    mr[DIM + c] = rsqrtf(v + EPS_BN);
}

__global__ __launch_bounds__(256) void bn_apply_kernel(const float* __restrict__ Cin, float* __restrict__ A,
                                                       const float* __restrict__ mr, const float* __restrict__ g,
                                                       const float* __restrict__ b, int n, int relu, int residual) {
    int c = threadIdx.x;
    float mean = mr[c], rstd = mr[DIM + c], gg = g[c], bb = b[c];
    for (int i = blockIdx.x; i < n; i += gridDim.x) {
        size_t idx = (size_t)i * DIM + c;
        float v = Cin[idx];
        if (relu) v = fmaxf(v, 0.f);
        v = (v - mean) * rstd * gg + bb;
        if (residual) A[idx] += v; else A[idx] = v;
    }
}

// ============================ degree / CSR build ============================
__global__ void count_int_kernel(const int* __restrict__ idx, int n, int* __restrict__ cnt) {
    for (int i = blockIdx.x * blockDim.x + threadIdx.x; i < n; i += gridDim.x * blockDim.x)
        atomicAdd(&cnt[idx[i]], 1);
}

__global__ void dinv_kernel(const int* __restrict__ cnt, float* __restrict__ dinv, int n) {
    for (int i = blockIdx.x * blockDim.x + threadIdx.x; i < n; i += gridDim.x * blockDim.x)
        dinv[i] = rsqrtf((float)cnt[i] + 1.0f);
}

#define SCHUNK 2048
__global__ __launch_bounds__(256) void scan1_kernel(const int* __restrict__ cnt, int n,
                                                    int* __restrict__ outp, int* __restrict__ bsums) {
    __shared__ int lds[256];
    int t = threadIdx.x;
    int base = blockIdx.x * SCHUNK + t * 8;
    int v[8]; int s = 0;
#pragma unroll
    for (int j = 0; j < 8; j++) { int id = base + j; int x = (id < n) ? cnt[id] : 0; v[j] = s; s += x; }
    lds[t] = s; __syncthreads();
    for (int o = 1; o < 256; o <<= 1) {
        int add = (t >= o) ? lds[t - o] : 0;
        __syncthreads();
        lds[t] += add;
        __syncthreads();
    }
    int excl = lds[t] - s;
#pragma unroll
    for (int j = 0; j < 8; j++) { int id = base + j; if (id < n) outp[id] = excl + v[j]; }
    if (t == 255) bsums[blockIdx.x] = lds[255];
}

__global__ void scan2_kernel(int* bsums, int nb) {
    if (threadIdx.x == 0 && blockIdx.x == 0) {
        int r = 0;
        for (int i = 0; i < nb; i++) { int t = bsums[i]; bsums[i] = r; r += t; }
    }
}

__global__ void scan3_kernel(int* __restrict__ outp, const int* __restrict__ bsums, int n, int total) {
    int i = blockIdx.x * blockDim.x + threadIdx.x;
    if (i < n) outp[i] += bsums[i / SCHUNK];
    if (i == 0) outp[n] = total;
}

__global__ void scatter_kernel(const int* __restrict__ src, const int* __restrict__ dst, int ne,
                               const int* __restrict__ rowp, int* __restrict__ fill, int* __restrict__ ss) {
    for (int e = blockIdx.x * blockDim.x + threadIdx.x; e < ne; e += gridDim.x * blockDim.x) {
        int d = dst[e];
        int pos = rowp[d] + atomicAdd(&fill[d], 1);
        ss[pos] = src[e];
    }
}

// ============================ GCN edge aggregation ============================
// out[row,:] = dinv[row]*sum_e dinv[src_e]*h[src_e,:] + dinv[row]^2*h[row,:] + bias
__global__ __launch_bounds__(256) void gcn_agg_kernel(const float* __restrict__ h, const int* __restrict__ rowp,
                                                      const int* __restrict__ ss, const float* __restrict__ dinv,
                                                      const float* __restrict__ bias, float* __restrict__ out, int n) {
    int wave = threadIdx.x >> 6;
    int lane = threadIdx.x & 63;
    int row = blockIdx.x * 4 + wave;
    if (row >= n) return;
    int c = lane * 4;
    float ax = 0.f, ay = 0.f, az = 0.f, aw = 0.f;
    int e0 = rowp[row], e1 = rowp[row + 1];
    for (int e = e0; e < e1; e++) {
        int s = ss[e];
        float w = dinv[s];
        float4 hv = *(const float4*)&h[(size_t)s * DIM + c];
        ax += w * hv.x; ay += w * hv.y; az += w * hv.z; aw += w * hv.w;
    }
    float di = dinv[row];
    float d2 = di * di;
    float4 hs = *(const float4*)&h[(size_t)row * DIM + c];
    float4 bv = *(const float4*)&bias[c];
    float4 r;
    r.x = di * ax + d2 * hs.x + bv.x;
    r.y = di * ay + d2 * hs.y + bv.y;
    r.z = di * az + d2 * hs.z + bv.z;
    r.w = di * aw + d2 * hs.w + bv.w;
    *(float4*)&out[(size_t)row * DIM + c] = r;
}

// ============================ fp32 GEMM: C[n,M] = A[n,K] @ W[K,M] ============================
#define GBM 128
#define GBN 128
#define GBK 32
__global__ __launch_bounds__(256) void gemm_kernel(const float* __restrict__ A, const float* __restrict__ W,
                                                   float* __restrict__ C, int n, int K, int M) {
    __shared__ __align__(16) float As[GBK][GBM + 4];
    __shared__ __align__(16) float Bs[GBK][GBN + 4];
    int tid = threadIdx.x;
    int tx = tid & 15, ty = tid >> 4;
    int bm = blockIdx.x * GBM, bn = blockIdx.y * GBN;
    float acc[8][8] = {};
    for (int k0 = 0; k0 < K; k0 += GBK) {
        {
            int r = tid >> 3;             // 0..31
            int kc = (tid & 7) * 4;       // 0..28
#pragma unroll
            for (int rr = r; rr < GBM; rr += 32) {
                int grow = bm + rr; if (grow >= n) grow = n - 1;
                float4 av = *(const float4*)&A[(size_t)grow * K + k0 + kc];
                As[kc + 0][rr] = av.x; As[kc + 1][rr] = av.y;
                As[kc + 2][rr] = av.z; As[kc + 3][rr] = av.w;
            }
            int kb = tid >> 5;            // 0..7
            int c4 = (tid & 31) * 4;      // 0..124
#pragma unroll
            for (int kk = kb; kk < GBK; kk += 8) {
                float4 bv = *(const float4*)&W[(size_t)(k0 + kk) * M + bn + c4];
                *(float4*)&Bs[kk][c4] = bv;
            }
        }
        __syncthreads();
#pragma unroll
        for (int k = 0; k < GBK; k++) {
            float4 a0 = *(float4*)&As[k][ty * 8];
            float4 a1 = *(float4*)&As[k][ty * 8 + 4];
            float4 b0 = *(float4*)&Bs[k][tx * 8];
            float4 b1 = *(float4*)&Bs[k][tx * 8 + 4];
            float av[8] = {a0.x, a0.y, a0.z, a0.w, a1.x, a1.y, a1.z, a1.w};
            float bv[8] = {b0.x, b0.y, b0.z, b0.w, b1.x, b1.y, b1.z, b1.w};
#pragma unroll
            for (int i = 0; i < 8; i++)
#pragma unroll
                for (int j = 0; j < 8; j++)
                    acc[i][j] += av[i] * bv[j];
        }
        __syncthreads();
    }
#pragma unroll
    for (int i = 0; i < 8; i++) {
        int row = bm + ty * 8 + i;
        if (row < n) {
            float4 s0 = make_float4(acc[i][0], acc[i][1], acc[i][2], acc[i][3]);
            float4 s1 = make_float4(acc[i][4], acc[i][5], acc[i][6], acc[i][7]);
            *(float4*)&C[(size_t)row * M + bn + tx * 8] = s0;
            *(float4*)&C[(size_t)row * M + bn + tx * 8 + 4] = s1;
        }
    }
}

// ============================ attention ============================
__global__ __launch_bounds__(256) void attn_score_kernel(const float* __restrict__ T, const float* __restrict__ ba1,
                                                         const float* __restrict__ Wa2, const float* __restrict__ ba2,
                                                         float* __restrict__ score, int n) {
    int wave = threadIdx.x >> 6, lane = threadIdx.x & 63;
    int row = blockIdx.x * 4 + wave;
    if (row >= n) return;
    float s = 0.f;
#pragma unroll
    for (int j = lane; j < 128; j += 64) {
        float v = T[(size_t)row * 128 + j] + ba1[j];
        v = (v > 0.f) ? v : 0.01f * v;
        s += v * Wa2[j];
    }
    for (int o = 32; o > 0; o >>= 1) s += __shfl_down(s, o);
    if (lane == 0) score[row] = s + ba2[0];
}

__global__ __launch_bounds__(256) void reduce_max_kernel(const float* __restrict__ s, int n, float* __restrict__ part) {
    __shared__ float lds[256];
    float m = -3.0e38f;
    for (int i = blockIdx.x * 256 + threadIdx.x; i < n; i += gridDim.x * 256) m = fmaxf(m, s[i]);
    lds[threadIdx.x] = m; __syncthreads();
    for (int o = 128; o > 0; o >>= 1) {
        if (threadIdx.x < o) lds[threadIdx.x] = fmaxf(lds[threadIdx.x], lds[threadIdx.x + o]);
        __syncthreads();
    }
    if (threadIdx.x == 0) part[blockIdx.x] = lds[0];
}

__global__ void reduce_max_final_kernel(const float* __restrict__ part, int nb, float* __restrict__ red) {
    __shared__ float lds[256];
    float m = -3.0e38f;
    for (int i = threadIdx.x; i < nb; i += 256) m = fmaxf(m, part[i]);
    lds[threadIdx.x] = m; __syncthreads();
    for (int o = 128; o > 0; o >>= 1) {
        if (threadIdx.x < o) lds[threadIdx.x] = fmaxf(lds[threadIdx.x], lds[threadIdx.x + o]);
        __syncthreads();
    }
    if (threadIdx.x == 0) red[0] = lds[0];
}

__global__ __launch_bounds__(256) void reduce_sumexp_kernel(const float* __restrict__ s, int n,
                                                            const float* __restrict__ red, float* __restrict__ part) {
    __shared__ float lds[256];
    float mx = red[0];
    float acc = 0.f;
    for (int i = blockIdx.x * 256 + threadIdx.x; i < n; i += gridDim.x * 256) acc += expf(s[i] - mx);
    lds[threadIdx.x] = acc; __syncthreads();
    for (int o = 128; o > 0; o >>= 1) {
        if (threadIdx.x < o) lds[threadIdx.x] += lds[threadIdx.x + o];
        __syncthreads();
    }
    if (threadIdx.x == 0) part[blockIdx.x] = lds[0];
}

__global__ void reduce_sum_final_kernel(const float* __restrict__ part, int nb, float* __restrict__ red) {
    __shared__ float lds[256];
    float s = 0.f;
    for (int i = threadIdx.x; i < nb; i += 256) s += part[i];
    lds[threadIdx.x] = s; __syncthreads();
    for (int o = 128; o > 0; o >>= 1) {
        if (threadIdx.x < o) lds[threadIdx.x] += lds[threadIdx.x + o];
        __syncthreads();
    }
    if (threadIdx.x == 0) red[1] = lds[0];
}

__global__ void graph_offsets_kernel(const int* __restrict__ cnt, int* __restrict__ off) {
    if (threadIdx.x == 0 && blockIdx.x == 0) {
        int r = 0;
        for (int g = 0; g < NG; g++) { off[g] = r; r += cnt[g]; }
    }
}

// pooled[g,c] += sum over striped nodes of A[i,c]*exp(score[i]-mx); grid (NG, 8)
__global__ __launch_bounds__(256) void pool_kernel(const float* __restrict__ A, const float* __restrict__ score,
                                                   const int* __restrict__ offs, const int* __restrict__ cnts,
                                                   const float* __restrict__ red, float* __restrict__ pooled) {
    int g = blockIdx.x, c = threadIdx.x;
    int st = offs[g], cn = cnts[g];
    float mx = red[0];
    float acc = 0.f;
    for (int i = (int)blockIdx.y; i < cn; i += 32) {
        int i1 = i + 8, i2 = i + 16, i3 = i + 24;
        float s0 = score[st + i];
        float s1 = (i1 < cn) ? score[st + i1] : -3.0e38f;
        float s2 = (i2 < cn) ? score[st + i2] : -3.0e38f;
        float s3 = (i3 < cn) ? score[st + i3] : -3.0e38f;
        float a0 = A[(size_t)(st + i) * DIM + c];
        float a1 = (i1 < cn) ? A[(size_t)(st + i1) * DIM + c] : 0.f;
        float a2 = (i2 < cn) ? A[(size_t)(st + i2) * DIM + c] : 0.f;
        float a3 = (i3 < cn) ? A[(size_t)(st + i3) * DIM + c] : 0.f;
        acc += a0 * expf(s0 - mx) + a1 * expf(s1 - mx) + a2 * expf(s2 - mx) + a3 * expf(s3 - mx);
    }
    atomicAdd(&pooled[g * DIM + c], acc);
}

__global__ __launch_bounds__(256) void out_kernel(const float* __restrict__ pooled, const int* __restrict__ cnt,
                                                  const float* __restrict__ red, const float* __restrict__ Wo,
                                                  const float* __restrict__ bo, float* __restrict__ out) {
    __shared__ float l0[256], l1[256];
    int g = blockIdx.x, c = threadIdx.x;
    float scale = 1.f / (red[1] * fmaxf((float)cnt[g], 1.f));
    float v = pooled[g * DIM + c] * scale;
    l0[c] = v * Wo[c * 2];
    l1[c] = v * Wo[c * 2 + 1];
    __syncthreads();
    for (int o = 128; o > 0; o >>= 1) {
        if (c < o) { l0[c] += l0[c + o]; l1[c] += l1[c + o]; }
        __syncthreads();
    }
    if (c == 0) { out[g * 2] = l0[0] + bo[0]; out[g * 2 + 1] = l1[0] + bo[1]; }
}

// ============================ launch ============================
extern "C" void kernel_launch(void* const* d_in, const int* in_sizes, int n_in,
                              void* d_out, int out_size, void* d_ws, size_t ws_size,
                              hipStream_t stream) {
    const float* x       = (const float*)d_in[0];
    const int*   ei      = (const int*)d_in[1];
    const int*   batch   = (const int*)d_in[2];
    const float* bn_in_g = (const float*)d_in[3];
    const float* bn_in_b = (const float*)d_in[4];
    const float* Ws[3]   = {(const float*)d_in[5],  (const float*)d_in[9],  (const float*)d_in[13]};
    const float* bs[3]   = {(const float*)d_in[6],  (const float*)d_in[10], (const float*)d_in[14]};
    const float* gs[3]   = {(const float*)d_in[7],  (const float*)d_in[11], (const float*)d_in[15]};
    const float* bbs[3]  = {(const float*)d_in[8],  (const float*)d_in[12], (const float*)d_in[16]};
    const float* Wa1 = (const float*)d_in[17];
    const float* ba1 = (const float*)d_in[18];
    const float* Wa2 = (const float*)d_in[19];
    const float* ba2 = (const float*)d_in[20];
    const float* Wo  = (const float*)d_in[21];
    const float* bo  = (const float*)d_in[22];

    char* w = (char*)d_ws;
    size_t off = 0;
    auto alloc = [&](size_t bytes) -> void* {
        void* p = w + off;
        off += (bytes + 255) & ~(size_t)255;
        return p;
    };
    float* A    = (float*)alloc((size_t)N_NODES * DIM * 4);  // features (xp)
    float* B    = (float*)alloc((size_t)N_NODES * DIM * 4);  // h = xp @ W
    float* C    = (float*)alloc((size_t)N_NODES * DIM * 4);  // aggregated / attn intermediate
    int* sorted_src = (int*)alloc((size_t)N_EDGES * 4);
    int* deg    = (int*)alloc((size_t)N_NODES * 4);
    float* dinv = (float*)alloc((size_t)N_NODES * 4);
    int* rowp   = (int*)alloc((size_t)(N_NODES + 1) * 4);
    int* fill   = (int*)alloc((size_t)N_NODES * 4);
    float* score = (float*)alloc((size_t)N_NODES * 4);
    float* stats = (float*)alloc(512 * 4);
    float* mr    = (float*)alloc(512 * 4);
    int* bsums   = (int*)alloc(64 * 4);
    float* part  = (float*)alloc(256 * 4);
    float* red   = (float*)alloc(16 * 4);
    int* cnt_g   = (int*)alloc(64 * 4);
    int* off_g   = (int*)alloc(64 * 4);
    float* pooled = (float*)alloc((size_t)NG * DIM * 4);

    const int* src = ei;
    const int* dst = ei + N_EDGES;

    // ---- degree + CSR (dst-sorted edges) ----
    hipMemsetAsync(deg, 0, (size_t)N_NODES * 4, stream);
    hipMemsetAsync(fill, 0, (size_t)N_NODES * 4, stream);
    count_int_kernel<<<3125, 256, 0, stream>>>(dst, N_EDGES, deg);
    dinv_kernel<<<196, 256, 0, stream>>>(deg, dinv, N_NODES);
    scan1_kernel<<<(N_NODES + SCHUNK - 1) / SCHUNK, 256, 0, stream>>>(deg, N_NODES, rowp, bsums);
    scan2_kernel<<<1, 64, 0, stream>>>(bsums, (N_NODES + SCHUNK - 1) / SCHUNK);
    scan3_kernel<<<(N_NODES + 255) / 256, 256, 0, stream>>>(rowp, bsums, N_NODES, N_EDGES);
    scatter_kernel<<<3125, 256, 0, stream>>>(src, dst, N_EDGES, rowp, fill, sorted_src);

    // ---- input BN ----
    hipMemsetAsync(stats, 0, 512 * 4, stream);
    col_stats_kernel<<<512, 256, 0, stream>>>(x, N_NODES, stats, 0);
    finalize_stats_kernel<<<1, 256, 0, stream>>>(stats, mr, 1.f / N_NODES);
    bn_apply_kernel<<<1024, 256, 0, stream>>>(x, A, mr, bn_in_g, bn_in_b, N_NODES, 0, 0);

    // ---- GCN layers ----
    dim3 ggrid((N_NODES + GBM - 1) / GBM, DIM / GBN);
    for (int l = 0; l < 3; l++) {
        gemm_kernel<<<ggrid, 256, 0, stream>>>(A, Ws[l], B, N_NODES, DIM, DIM);
        gcn_agg_kernel<<<(N_NODES + 3) / 4, 256, 0, stream>>>(B, rowp, sorted_src, dinv, bs[l], C, N_NODES);
        hipMemsetAsync(stats, 0, 512 * 4, stream);
        col_stats_kernel<<<512, 256, 0, stream>>>(C, N_NODES, stats, 1);
        finalize_stats_kernel<<<1, 256, 0, stream>>>(stats, mr, 1.f / N_NODES);
        bn_apply_kernel<<<1024, 256, 0, stream>>>(C, A, mr, gs[l], bbs[l], N_NODES, 1, (l > 0) ? 1 : 0);
    }

    // ---- attention scores ----
    dim3 agrid((N_NODES + GBM - 1) / GBM, 1);
    gemm_kernel<<<agrid, 256, 0, stream>>>(A, Wa1, C, N_NODES, DIM, 128);
    attn_score_kernel<<<(N_NODES + 3) / 4, 256, 0, stream>>>(C, ba1, Wa2, ba2, score, N_NODES);
    reduce_max_kernel<<<256, 256, 0, stream>>>(score, N_NODES, part);
    reduce_max_final_kernel<<<1, 256, 0, stream>>>(part, 256, red);
    reduce_sumexp_kernel<<<256, 256, 0, stream>>>(score, N_NODES, red, part);
    reduce_sum_final_kernel<<<1, 256, 0, stream>>>(part, 256, red);

    // ---- per-graph pooling ----
    hipMemsetAsync(cnt_g, 0, 64 * 4, stream);
    hipMemsetAsync(pooled, 0, (size_t)NG * DIM * 4, stream);
    count_int_kernel<<<196, 256, 0, stream>>>(batch, N_NODES, cnt_g);
    graph_offsets_kernel<<<1, 64, 0, stream>>>(cnt_g, off_g);
    pool_kernel<<<dim3(NG, 8), 256, 0, stream>>>(A, score, off_g, cnt_g, red, pooled);
    out_kernel<<<NG, 256, 0, stream>>>(pooled, cnt_g, red, Wo, bo, (float*)d_out);
}

// Round 2
// 1548.568 us; speedup vs baseline: 1.1418x; 1.1418x over previous
//
#include <hip/hip_runtime.h>

#define N_NODES 50000
#define N_EDGES 800000
#define DIM 256
#define NG 64
#define EPS_BN 1e-5f

// ============================ BN statistics ============================
__global__ __launch_bounds__(256) void col_stats_kernel(const float* __restrict__ X, int n,
                                                        float* __restrict__ sums, int relu) {
    int c = threadIdx.x;
    float s = 0.f, q = 0.f;
    for (int i = blockIdx.x; i < n; i += gridDim.x) {
        float v = X[(size_t)i * DIM + c];
        if (relu) v = fmaxf(v, 0.f);
        s += v; q += v * v;
    }
    atomicAdd(&sums[c], s);
    atomicAdd(&sums[DIM + c], q);
}

__global__ void finalize_stats_kernel(const float* __restrict__ sums, float* __restrict__ mr, float inv_n) {
    int c = threadIdx.x;
    float m = sums[c] * inv_n;
    float v = sums[DIM + c] * inv_n - m * m;
    mr[c] = m;
    mr[DIM + c] = rsqrtf(v + EPS_BN);
}

__global__ __launch_bounds__(256) void bn_apply_kernel(const float* __restrict__ Cin, float* __restrict__ A,
                                                       const float* __restrict__ mr, const float* __restrict__ g,
                                                       const float* __restrict__ b, int n, int relu, int residual) {
    int c = threadIdx.x;
    float mean = mr[c], rstd = mr[DIM + c], gg = g[c], bb = b[c];
    for (int i = blockIdx.x; i < n; i += gridDim.x) {
        size_t idx = (size_t)i * DIM + c;
        float v = Cin[idx];
        if (relu) v = fmaxf(v, 0.f);
        v = (v - mean) * rstd * gg + bb;
        if (residual) A[idx] += v; else A[idx] = v;
    }
}

// ============================ degree / CSR build ============================
__global__ void count_int_kernel(const int* __restrict__ idx, int n, int* __restrict__ cnt) {
    for (int i = blockIdx.x * blockDim.x + threadIdx.x; i < n; i += gridDim.x * blockDim.x)
        atomicAdd(&cnt[idx[i]], 1);
}

__global__ void dinv_kernel(const int* __restrict__ cnt, float* __restrict__ dinv, int n) {
    for (int i = blockIdx.x * blockDim.x + threadIdx.x; i < n; i += gridDim.x * blockDim.x)
        dinv[i] = rsqrtf((float)cnt[i] + 1.0f);
}

#define SCHUNK 2048
__global__ __launch_bounds__(256) void scan1_kernel(const int* __restrict__ cnt, int n,
                                                    int* __restrict__ outp, int* __restrict__ bsums) {
    __shared__ int lds[256];
    int t = threadIdx.x;
    int base = blockIdx.x * SCHUNK + t * 8;
    int v[8]; int s = 0;
#pragma unroll
    for (int j = 0; j < 8; j++) { int id = base + j; int x = (id < n) ? cnt[id] : 0; v[j] = s; s += x; }
    lds[t] = s; __syncthreads();
    for (int o = 1; o < 256; o <<= 1) {
        int add = (t >= o) ? lds[t - o] : 0;
        __syncthreads();
        lds[t] += add;
        __syncthreads();
    }
    int excl = lds[t] - s;
#pragma unroll
    for (int j = 0; j < 8; j++) { int id = base + j; if (id < n) outp[id] = excl + v[j]; }
    if (t == 255) bsums[blockIdx.x] = lds[255];
}

__global__ void scan2_kernel(int* bsums, int nb) {
    if (threadIdx.x == 0 && blockIdx.x == 0) {
        int r = 0;
        for (int i = 0; i < nb; i++) { int t = bsums[i]; bsums[i] = r; r += t; }
    }
}

__global__ void scan3_kernel(int* __restrict__ outp, const int* __restrict__ bsums, int n, int total) {
    int i = blockIdx.x * blockDim.x + threadIdx.x;
    if (i < n) outp[i] += bsums[i / SCHUNK];
    if (i == 0) outp[n] = total;
}

__global__ void scatter_kernel(const int* __restrict__ src, const int* __restrict__ dst, int ne,
                               const int* __restrict__ rowp, int* __restrict__ fill, int* __restrict__ ss) {
    for (int e = blockIdx.x * blockDim.x + threadIdx.x; e < ne; e += gridDim.x * blockDim.x) {
        int d = dst[e];
        int pos = rowp[d] + atomicAdd(&fill[d], 1);
        ss[pos] = src[e];
    }
}

// ============================ graph ranges (batch is sorted -> no atomics) ============================
__global__ void graph_bounds_kernel(const int* __restrict__ batch, int n, int* __restrict__ start) {
    int i = blockIdx.x * blockDim.x + threadIdx.x;
    if (i < n) {
        int b = batch[i];
        if (i == 0 || batch[i - 1] != b) start[b] = i;
    }
}

__global__ void graph_offsets2_kernel(const int* __restrict__ start, int* __restrict__ off, int* __restrict__ cnt) {
    if (threadIdx.x == 0 && blockIdx.x == 0) {
        int nxt = N_NODES;
        for (int g = NG - 1; g >= 0; --g) {
            int s = start[g];
            int o = (s < 0) ? nxt : s;   // empty graph -> zero-length range
            off[g] = o;
            cnt[g] = nxt - o;
            nxt = o;
        }
    }
}

// ============================ GCN edge aggregation ============================
// out[row,:] = dinv[row]*sum_e dinv[src_e]*h[src_e,:] + dinv[row]^2*h[row,:] + bias
__global__ __launch_bounds__(256) void gcn_agg_kernel(const float* __restrict__ h, const int* __restrict__ rowp,
                                                      const int* __restrict__ ss, const float* __restrict__ dinv,
                                                      const float* __restrict__ bias, float* __restrict__ out, int n) {
    int wave = threadIdx.x >> 6;
    int lane = threadIdx.x & 63;
    int row = blockIdx.x * 4 + wave;
    if (row >= n) return;
    int c = lane * 4;
    float ax = 0.f, ay = 0.f, az = 0.f, aw = 0.f;
    int e0 = rowp[row], e1 = rowp[row + 1];
    int e = e0;
    // 4-way unrolled: 4 independent gather chains in flight
    for (; e + 3 < e1; e += 4) {
        int s0 = ss[e], s1 = ss[e + 1], s2 = ss[e + 2], s3 = ss[e + 3];
        float w0 = dinv[s0], w1 = dinv[s1], w2 = dinv[s2], w3 = dinv[s3];
        float4 h0 = *(const float4*)&h[(size_t)s0 * DIM + c];
        float4 h1 = *(const float4*)&h[(size_t)s1 * DIM + c];
        float4 h2 = *(const float4*)&h[(size_t)s2 * DIM + c];
        float4 h3 = *(const float4*)&h[(size_t)s3 * DIM + c];
        ax += w0 * h0.x + w1 * h1.x + w2 * h2.x + w3 * h3.x;
        ay += w0 * h0.y + w1 * h1.y + w2 * h2.y + w3 * h3.y;
        az += w0 * h0.z + w1 * h1.z + w2 * h2.z + w3 * h3.z;
        aw += w0 * h0.w + w1 * h1.w + w2 * h2.w + w3 * h3.w;
    }
    for (; e < e1; e++) {
        int s = ss[e];
        float w = dinv[s];
        float4 hv = *(const float4*)&h[(size_t)s * DIM + c];
        ax += w * hv.x; ay += w * hv.y; az += w * hv.z; aw += w * hv.w;
    }
    float di = dinv[row];
    float d2 = di * di;
    float4 hs = *(const float4*)&h[(size_t)row * DIM + c];
    float4 bv = *(const float4*)&bias[c];
    float4 r;
    r.x = di * ax + d2 * hs.x + bv.x;
    r.y = di * ay + d2 * hs.y + bv.y;
    r.z = di * az + d2 * hs.z + bv.z;
    r.w = di * aw + d2 * hs.w + bv.w;
    *(float4*)&out[(size_t)row * DIM + c] = r;
}

// ============================ fp32 GEMM: C[n,M] = A[n,K] @ W[K,M] ============================
#define GBM 128
#define GBN 128
#define GBK 32
__global__ __launch_bounds__(256) void gemm_kernel(const float* __restrict__ A, const float* __restrict__ W,
                                                   float* __restrict__ C, int n, int K, int M) {
    __shared__ __align__(16) float As[GBK][GBM + 4];
    __shared__ __align__(16) float Bs[GBK][GBN + 4];
    int tid = threadIdx.x;
    int tx = tid & 15, ty = tid >> 4;
    int bm = blockIdx.x * GBM, bn = blockIdx.y * GBN;
    float acc[8][8] = {};
    for (int k0 = 0; k0 < K; k0 += GBK) {
        {
            int r = tid >> 3;             // 0..31
            int kc = (tid & 7) * 4;       // 0..28
#pragma unroll
            for (int rr = r; rr < GBM; rr += 32) {
                int grow = bm + rr; if (grow >= n) grow = n - 1;
                float4 av = *(const float4*)&A[(size_t)grow * K + k0 + kc];
                As[kc + 0][rr] = av.x; As[kc + 1][rr] = av.y;
                As[kc + 2][rr] = av.z; As[kc + 3][rr] = av.w;
            }
            int kb = tid >> 5;            // 0..7
            int c4 = (tid & 31) * 4;      // 0..124
#pragma unroll
            for (int kk = kb; kk < GBK; kk += 8) {
                float4 bv = *(const float4*)&W[(size_t)(k0 + kk) * M + bn + c4];
                *(float4*)&Bs[kk][c4] = bv;
            }
        }
        __syncthreads();
#pragma unroll
        for (int k = 0; k < GBK; k++) {
            float4 a0 = *(float4*)&As[k][ty * 8];
            float4 a1 = *(float4*)&As[k][ty * 8 + 4];
            float4 b0 = *(float4*)&Bs[k][tx * 8];
            float4 b1 = *(float4*)&Bs[k][tx * 8 + 4];
            float av[8] = {a0.x, a0.y, a0.z, a0.w, a1.x, a1.y, a1.z, a1.w};
            float bv[8] = {b0.x, b0.y, b0.z, b0.w, b1.x, b1.y, b1.z, b1.w};
#pragma unroll
            for (int i = 0; i < 8; i++)
#pragma unroll
                for (int j = 0; j < 8; j++)
                    acc[i][j] += av[i] * bv[j];
        }
        __syncthreads();
    }
#pragma unroll
    for (int i = 0; i < 8; i++) {
        int row = bm + ty * 8 + i;
        if (row < n) {
            float4 s0 = make_float4(acc[i][0], acc[i][1], acc[i][2], acc[i][3]);
            float4 s1 = make_float4(acc[i][4], acc[i][5], acc[i][6], acc[i][7]);
            *(float4*)&C[(size_t)row * M + bn + tx * 8] = s0;
            *(float4*)&C[(size_t)row * M + bn + tx * 8 + 4] = s1;
        }
    }
}

// ============================ attention ============================
__global__ __launch_bounds__(256) void attn_score_kernel(const float* __restrict__ T, const float* __restrict__ ba1,
                                                         const float* __restrict__ Wa2, const float* __restrict__ ba2,
                                                         float* __restrict__ score, int n) {
    int wave = threadIdx.x >> 6, lane = threadIdx.x & 63;
    int row = blockIdx.x * 4 + wave;
    if (row >= n) return;
    float s = 0.f;
#pragma unroll
    for (int j = lane; j < 128; j += 64) {
        float v = T[(size_t)row * 128 + j] + ba1[j];
        v = (v > 0.f) ? v : 0.01f * v;
        s += v * Wa2[j];
    }
    for (int o = 32; o > 0; o >>= 1) s += __shfl_down(s, o);
    if (lane == 0) score[row] = s + ba2[0];
}

__global__ __launch_bounds__(256) void reduce_max_kernel(const float* __restrict__ s, int n, float* __restrict__ part) {
    __shared__ float lds[256];
    float m = -3.0e38f;
    for (int i = blockIdx.x * 256 + threadIdx.x; i < n; i += gridDim.x * 256) m = fmaxf(m, s[i]);
    lds[threadIdx.x] = m; __syncthreads();
    for (int o = 128; o > 0; o >>= 1) {
        if (threadIdx.x < o) lds[threadIdx.x] = fmaxf(lds[threadIdx.x], lds[threadIdx.x + o]);
        __syncthreads();
    }
    if (threadIdx.x == 0) part[blockIdx.x] = lds[0];
}

__global__ void reduce_max_final_kernel(const float* __restrict__ part, int nb, float* __restrict__ red) {
    __shared__ float lds[256];
    float m = -3.0e38f;
    for (int i = threadIdx.x; i < nb; i += 256) m = fmaxf(m, part[i]);
    lds[threadIdx.x] = m; __syncthreads();
    for (int o = 128; o > 0; o >>= 1) {
        if (threadIdx.x < o) lds[threadIdx.x] = fmaxf(lds[threadIdx.x], lds[threadIdx.x + o]);
        __syncthreads();
    }
    if (threadIdx.x == 0) red[0] = lds[0];
}

__global__ __launch_bounds__(256) void reduce_sumexp_kernel(const float* __restrict__ s, int n,
                                                            const float* __restrict__ red, float* __restrict__ part) {
    __shared__ float lds[256];
    float mx = red[0];
    float acc = 0.f;
    for (int i = blockIdx.x * 256 + threadIdx.x; i < n; i += gridDim.x * 256) acc += expf(s[i] - mx);
    lds[threadIdx.x] = acc; __syncthreads();
    for (int o = 128; o > 0; o >>= 1) {
        if (threadIdx.x < o) lds[threadIdx.x] += lds[threadIdx.x + o];
        __syncthreads();
    }
    if (threadIdx.x == 0) part[blockIdx.x] = lds[0];
}

__global__ void reduce_sum_final_kernel(const float* __restrict__ part, int nb, float* __restrict__ red) {
    __shared__ float lds[256];
    float s = 0.f;
    for (int i = threadIdx.x; i < nb; i += 256) s += part[i];
    lds[threadIdx.x] = s; __syncthreads();
    for (int o = 128; o > 0; o >>= 1) {
        if (threadIdx.x < o) lds[threadIdx.x] += lds[threadIdx.x + o];
        __syncthreads();
    }
    if (threadIdx.x == 0) red[1] = lds[0];
}

// pooled[g,c] += sum over striped nodes of A[i,c]*exp(score[i]-mx); grid (NG, 8)
__global__ __launch_bounds__(256) void pool_kernel(const float* __restrict__ A, const float* __restrict__ score,
                                                   const int* __restrict__ offs, const int* __restrict__ cnts,
                                                   const float* __restrict__ red, float* __restrict__ pooled) {
    int g = blockIdx.x, c = threadIdx.x;
    int st = offs[g], cn = cnts[g];
    float mx = red[0];
    float acc = 0.f;
    for (int i = (int)blockIdx.y; i < cn; i += 32) {
        int i1 = i + 8, i2 = i + 16, i3 = i + 24;
        float s0 = score[st + i];
        float s1 = (i1 < cn) ? score[st + i1] : -3.0e38f;
        float s2 = (i2 < cn) ? score[st + i2] : -3.0e38f;
        float s3 = (i3 < cn) ? score[st + i3] : -3.0e38f;
        float a0 = A[(size_t)(st + i) * DIM + c];
        float a1 = (i1 < cn) ? A[(size_t)(st + i1) * DIM + c] : 0.f;
        float a2 = (i2 < cn) ? A[(size_t)(st + i2) * DIM + c] : 0.f;
        float a3 = (i3 < cn) ? A[(size_t)(st + i3) * DIM + c] : 0.f;
        acc += a0 * expf(s0 - mx) + a1 * expf(s1 - mx) + a2 * expf(s2 - mx) + a3 * expf(s3 - mx);
    }
    atomicAdd(&pooled[g * DIM + c], acc);
}

__global__ __launch_bounds__(256) void out_kernel(const float* __restrict__ pooled, const int* __restrict__ cnt,
                                                  const float* __restrict__ red, const float* __restrict__ Wo,
                                                  const float* __restrict__ bo, float* __restrict__ out) {
    __shared__ float l0[256], l1[256];
    int g = blockIdx.x, c = threadIdx.x;
    float scale = 1.f / (red[1] * fmaxf((float)cnt[g], 1.f));
    float v = pooled[g * DIM + c] * scale;
    l0[c] = v * Wo[c * 2];
    l1[c] = v * Wo[c * 2 + 1];
    __syncthreads();
    for (int o = 128; o > 0; o >>= 1) {
        if (c < o) { l0[c] += l0[c + o]; l1[c] += l1[c + o]; }
        __syncthreads();
    }
    if (c == 0) { out[g * 2] = l0[0] + bo[0]; out[g * 2 + 1] = l1[0] + bo[1]; }
}

// ============================ launch ============================
extern "C" void kernel_launch(void* const* d_in, const int* in_sizes, int n_in,
                              void* d_out, int out_size, void* d_ws, size_t ws_size,
                              hipStream_t stream) {
    const float* x       = (const float*)d_in[0];
    const int*   ei      = (const int*)d_in[1];
    const int*   batch   = (const int*)d_in[2];
    const float* bn_in_g = (const float*)d_in[3];
    const float* bn_in_b = (const float*)d_in[4];
    const float* Ws[3]   = {(const float*)d_in[5],  (const float*)d_in[9],  (const float*)d_in[13]};
    const float* bs[3]   = {(const float*)d_in[6],  (const float*)d_in[10], (const float*)d_in[14]};
    const float* gs[3]   = {(const float*)d_in[7],  (const float*)d_in[11], (const float*)d_in[15]};
    const float* bbs[3]  = {(const float*)d_in[8],  (const float*)d_in[12], (const float*)d_in[16]};
    const float* Wa1 = (const float*)d_in[17];
    const float* ba1 = (const float*)d_in[18];
    const float* Wa2 = (const float*)d_in[19];
    const float* ba2 = (const float*)d_in[20];
    const float* Wo  = (const float*)d_in[21];
    const float* bo  = (const float*)d_in[22];

    char* w = (char*)d_ws;
    size_t off = 0;
    auto alloc = [&](size_t bytes) -> void* {
        void* p = w + off;
        off += (bytes + 255) & ~(size_t)255;
        return p;
    };
    float* A    = (float*)alloc((size_t)N_NODES * DIM * 4);  // features (xp)
    float* B    = (float*)alloc((size_t)N_NODES * DIM * 4);  // h = xp @ W
    float* C    = (float*)alloc((size_t)N_NODES * DIM * 4);  // aggregated / attn intermediate
    int* sorted_src = (int*)alloc((size_t)N_EDGES * 4);
    int* deg    = (int*)alloc((size_t)N_NODES * 4);
    float* dinv = (float*)alloc((size_t)N_NODES * 4);
    int* rowp   = (int*)alloc((size_t)(N_NODES + 1) * 4);
    int* fill   = (int*)alloc((size_t)N_NODES * 4);
    float* score = (float*)alloc((size_t)N_NODES * 4);
    float* stats = (float*)alloc(512 * 4);
    float* mr    = (float*)alloc(512 * 4);
    int* bsums   = (int*)alloc(64 * 4);
    float* part  = (float*)alloc(256 * 4);
    float* red   = (float*)alloc(16 * 4);
    int* gstart  = (int*)alloc(64 * 4);
    int* cnt_g   = (int*)alloc(64 * 4);
    int* off_g   = (int*)alloc(64 * 4);
    float* pooled = (float*)alloc((size_t)NG * DIM * 4);

    const int* src = ei;
    const int* dst = ei + N_EDGES;

    // ---- degree + CSR (dst-sorted edges) ----
    hipMemsetAsync(deg, 0, (size_t)N_NODES * 4, stream);
    hipMemsetAsync(fill, 0, (size_t)N_NODES * 4, stream);
    count_int_kernel<<<3125, 256, 0, stream>>>(dst, N_EDGES, deg);
    dinv_kernel<<<196, 256, 0, stream>>>(deg, dinv, N_NODES);
    scan1_kernel<<<(N_NODES + SCHUNK - 1) / SCHUNK, 256, 0, stream>>>(deg, N_NODES, rowp, bsums);
    scan2_kernel<<<1, 64, 0, stream>>>(bsums, (N_NODES + SCHUNK - 1) / SCHUNK);
    scan3_kernel<<<(N_NODES + 255) / 256, 256, 0, stream>>>(rowp, bsums, N_NODES, N_EDGES);
    scatter_kernel<<<3125, 256, 0, stream>>>(src, dst, N_EDGES, rowp, fill, sorted_src);

    // ---- graph ranges from sorted batch (no atomics) ----
    hipMemsetAsync(gstart, 0xff, 64 * 4, stream);
    graph_bounds_kernel<<<(N_NODES + 255) / 256, 256, 0, stream>>>(batch, N_NODES, gstart);
    graph_offsets2_kernel<<<1, 64, 0, stream>>>(gstart, off_g, cnt_g);

    // ---- input BN ----
    hipMemsetAsync(stats, 0, 512 * 4, stream);
    col_stats_kernel<<<512, 256, 0, stream>>>(x, N_NODES, stats, 0);
    finalize_stats_kernel<<<1, 256, 0, stream>>>(stats, mr, 1.f / N_NODES);
    bn_apply_kernel<<<1024, 256, 0, stream>>>(x, A, mr, bn_in_g, bn_in_b, N_NODES, 0, 0);

    // ---- GCN layers ----
    dim3 ggrid((N_NODES + GBM - 1) / GBM, DIM / GBN);
    for (int l = 0; l < 3; l++) {
        gemm_kernel<<<ggrid, 256, 0, stream>>>(A, Ws[l], B, N_NODES, DIM, DIM);
        gcn_agg_kernel<<<(N_NODES + 3) / 4, 256, 0, stream>>>(B, rowp, sorted_src, dinv, bs[l], C, N_NODES);
        hipMemsetAsync(stats, 0, 512 * 4, stream);
        col_stats_kernel<<<512, 256, 0, stream>>>(C, N_NODES, stats, 1);
        finalize_stats_kernel<<<1, 256, 0, stream>>>(stats, mr, 1.f / N_NODES);
        bn_apply_kernel<<<1024, 256, 0, stream>>>(C, A, mr, gs[l], bbs[l], N_NODES, 1, (l > 0) ? 1 : 0);
    }

    // ---- attention scores ----
    dim3 agrid((N_NODES + GBM - 1) / GBM, 1);
    gemm_kernel<<<agrid, 256, 0, stream>>>(A, Wa1, C, N_NODES, DIM, 128);
    attn_score_kernel<<<(N_NODES + 3) / 4, 256, 0, stream>>>(C, ba1, Wa2, ba2, score, N_NODES);
    reduce_max_kernel<<<256, 256, 0, stream>>>(score, N_NODES, part);
    reduce_max_final_kernel<<<1, 256, 0, stream>>>(part, 256, red);
    reduce_sumexp_kernel<<<256, 256, 0, stream>>>(score, N_NODES, red, part);
    reduce_sum_final_kernel<<<1, 256, 0, stream>>>(part, 256, red);

    // ---- per-graph pooling ----
    hipMemsetAsync(pooled, 0, (size_t)NG * DIM * 4, stream);
    pool_kernel<<<dim3(NG, 8), 256, 0, stream>>>(A, score, off_g, cnt_g, red, pooled);
    out_kernel<<<NG, 256, 0, stream>>>(pooled, cnt_g, red, Wo, bo, (float*)d_out);
}

// Round 3
// 1009.317 us; speedup vs baseline: 1.7518x; 1.5343x over previous
//
#include <hip/hip_runtime.h>

#define N_NODES 50000
#define N_EDGES 800000
#define DIM 256
#define NG 64
#define EPS_BN 1e-5f

typedef _Float16 f16;
typedef _Float16 half8 __attribute__((ext_vector_type(8)));
typedef float floatx4 __attribute__((ext_vector_type(4)));

// ============================ BN statistics ============================
__global__ __launch_bounds__(256) void col_stats_kernel(const float* __restrict__ X, int n,
                                                        float* __restrict__ sums, int relu) {
    int c = threadIdx.x;
    float s = 0.f, q = 0.f;
    for (int i = blockIdx.x; i < n; i += gridDim.x) {
        float v = X[(size_t)i * DIM + c];
        if (relu) v = fmaxf(v, 0.f);
        s += v; q += v * v;
    }
    atomicAdd(&sums[c], s);
    atomicAdd(&sums[DIM + c], q);
}

__global__ void finalize_stats_kernel(const float* __restrict__ sums, float* __restrict__ mr, float inv_n) {
    int c = threadIdx.x;
    float m = sums[c] * inv_n;
    float v = sums[DIM + c] * inv_n - m * m;
    mr[c] = m;
    mr[DIM + c] = rsqrtf(v + EPS_BN);
}

// writes fp32 A (for residual/pooling) and fp16 Af (GEMM input)
__global__ __launch_bounds__(256) void bn_apply_kernel(const float* __restrict__ Cin, float* __restrict__ A,
                                                       f16* __restrict__ Af,
                                                       const float* __restrict__ mr, const float* __restrict__ g,
                                                       const float* __restrict__ b, int n, int relu, int residual) {
    int c = threadIdx.x;
    float mean = mr[c], rstd = mr[DIM + c], gg = g[c], bb = b[c];
    for (int i = blockIdx.x; i < n; i += gridDim.x) {
        size_t idx = (size_t)i * DIM + c;
        float v = Cin[idx];
        if (relu) v = fmaxf(v, 0.f);
        v = (v - mean) * rstd * gg + bb;
        if (residual) v += A[idx];
        A[idx] = v;
        Af[idx] = (f16)v;
    }
}

// ============================ weight conversion: Wt[m][k] = (f16)W[k][m] ============================
__global__ void convert_wT_kernel(const float* __restrict__ W, f16* __restrict__ Wt, int K, int M) {
    int idx = blockIdx.x * 256 + threadIdx.x;
    if (idx < K * M) {
        int m = idx / K, k = idx % K;
        Wt[idx] = (f16)W[(size_t)k * M + m];
    }
}

// ============================ degree / CSR build ============================
__global__ void count_int_kernel(const int* __restrict__ idx, int n, int* __restrict__ cnt) {
    for (int i = blockIdx.x * blockDim.x + threadIdx.x; i < n; i += gridDim.x * blockDim.x)
        atomicAdd(&cnt[idx[i]], 1);
}

__global__ void dinv_kernel(const int* __restrict__ cnt, float* __restrict__ dinv, int n) {
    for (int i = blockIdx.x * blockDim.x + threadIdx.x; i < n; i += gridDim.x * blockDim.x)
        dinv[i] = rsqrtf((float)cnt[i] + 1.0f);
}

#define SCHUNK 2048
__global__ __launch_bounds__(256) void scan1_kernel(const int* __restrict__ cnt, int n,
                                                    int* __restrict__ outp, int* __restrict__ bsums) {
    __shared__ int lds[256];
    int t = threadIdx.x;
    int base = blockIdx.x * SCHUNK + t * 8;
    int v[8]; int s = 0;
#pragma unroll
    for (int j = 0; j < 8; j++) { int id = base + j; int x = (id < n) ? cnt[id] : 0; v[j] = s; s += x; }
    lds[t] = s; __syncthreads();
    for (int o = 1; o < 256; o <<= 1) {
        int add = (t >= o) ? lds[t - o] : 0;
        __syncthreads();
        lds[t] += add;
        __syncthreads();
    }
    int excl = lds[t] - s;
#pragma unroll
    for (int j = 0; j < 8; j++) { int id = base + j; if (id < n) outp[id] = excl + v[j]; }
    if (t == 255) bsums[blockIdx.x] = lds[255];
}

__global__ void scan2_kernel(int* bsums, int nb) {
    if (threadIdx.x == 0 && blockIdx.x == 0) {
        int r = 0;
        for (int i = 0; i < nb; i++) { int t = bsums[i]; bsums[i] = r; r += t; }
    }
}

__global__ void scan3_kernel(int* __restrict__ outp, const int* __restrict__ bsums, int n, int total) {
    int i = blockIdx.x * blockDim.x + threadIdx.x;
    if (i < n) outp[i] += bsums[i / SCHUNK];
    if (i == 0) outp[n] = total;
}

__global__ void scatter_kernel(const int* __restrict__ src, const int* __restrict__ dst, int ne,
                               const int* __restrict__ rowp, int* __restrict__ fill, int* __restrict__ ss) {
    for (int e = blockIdx.x * blockDim.x + threadIdx.x; e < ne; e += gridDim.x * blockDim.x) {
        int d = dst[e];
        int pos = rowp[d] + atomicAdd(&fill[d], 1);
        ss[pos] = src[e];
    }
}

// ============================ graph ranges (batch sorted -> no atomics) ============================
__global__ void graph_bounds_kernel(const int* __restrict__ batch, int n, int* __restrict__ start) {
    int i = blockIdx.x * blockDim.x + threadIdx.x;
    if (i < n) {
        int b = batch[i];
        if (i == 0 || batch[i - 1] != b) start[b] = i;
    }
}

__global__ void graph_offsets2_kernel(const int* __restrict__ start, int* __restrict__ off, int* __restrict__ cnt) {
    if (threadIdx.x == 0 && blockIdx.x == 0) {
        int nxt = N_NODES;
        for (int g = NG - 1; g >= 0; --g) {
            int s = start[g];
            int o = (s < 0) ? nxt : s;
            off[g] = o;
            cnt[g] = nxt - o;
            nxt = o;
        }
    }
}

// ============================ GCN edge aggregation ============================
__global__ __launch_bounds__(256) void gcn_agg_kernel(const float* __restrict__ h, const int* __restrict__ rowp,
                                                      const int* __restrict__ ss, const float* __restrict__ dinv,
                                                      const float* __restrict__ bias, float* __restrict__ out, int n) {
    int wave = threadIdx.x >> 6;
    int lane = threadIdx.x & 63;
    int row = blockIdx.x * 4 + wave;
    if (row >= n) return;
    int c = lane * 4;
    float ax = 0.f, ay = 0.f, az = 0.f, aw = 0.f;
    int e0 = rowp[row], e1 = rowp[row + 1];
    int e = e0;
    for (; e + 3 < e1; e += 4) {
        int s0 = ss[e], s1 = ss[e + 1], s2 = ss[e + 2], s3 = ss[e + 3];
        float w0 = dinv[s0], w1 = dinv[s1], w2 = dinv[s2], w3 = dinv[s3];
        float4 h0 = *(const float4*)&h[(size_t)s0 * DIM + c];
        float4 h1 = *(const float4*)&h[(size_t)s1 * DIM + c];
        float4 h2 = *(const float4*)&h[(size_t)s2 * DIM + c];
        float4 h3 = *(const float4*)&h[(size_t)s3 * DIM + c];
        ax += w0 * h0.x + w1 * h1.x + w2 * h2.x + w3 * h3.x;
        ay += w0 * h0.y + w1 * h1.y + w2 * h2.y + w3 * h3.y;
        az += w0 * h0.z + w1 * h1.z + w2 * h2.z + w3 * h3.z;
        aw += w0 * h0.w + w1 * h1.w + w2 * h2.w + w3 * h3.w;
    }
    for (; e < e1; e++) {
        int s = ss[e];
        float w = dinv[s];
        float4 hv = *(const float4*)&h[(size_t)s * DIM + c];
        ax += w * hv.x; ay += w * hv.y; az += w * hv.z; aw += w * hv.w;
    }
    float di = dinv[row];
    float d2 = di * di;
    float4 hs = *(const float4*)&h[(size_t)row * DIM + c];
    float4 bv = *(const float4*)&bias[c];
    float4 r;
    r.x = di * ax + d2 * hs.x + bv.x;
    r.y = di * ay + d2 * hs.y + bv.y;
    r.z = di * az + d2 * hs.z + bv.z;
    r.w = di * aw + d2 * hs.w + bv.w;
    *(float4*)&out[(size_t)row * DIM + c] = r;
}

// ============================ fp16 MFMA GEMM: C[n,M] = Af[n,K] @ Wt^T ============================
// Af row-major [n][K] fp16; Wt [M][K] fp16 (i.e. W transposed, K contiguous)
#define BM 128
#define BN 128
#define BK 32
#define LDP 40   // padded LDS row stride in halfs: 2-way bank aliasing only
__global__ __launch_bounds__(256) void gemm_f16_kernel(const f16* __restrict__ Af, const f16* __restrict__ Wt,
                                                       float* __restrict__ C, int n, int K, int M) {
    __shared__ __align__(16) f16 As[BM * LDP];
    __shared__ __align__(16) f16 Bs[BN * LDP];
    int tid = threadIdx.x;
    int wave = tid >> 6, lane = tid & 63;
    int wm = wave >> 1, wn = wave & 1;
    int q = lane >> 4, l16 = lane & 15;
    int bm = blockIdx.x * BM, bn = blockIdx.y * BN;
    floatx4 acc[4][4] = {};
    for (int k0 = 0; k0 < K; k0 += BK) {
#pragma unroll
        for (int rr = 0; rr < 2; rr++) {
            int cidx = tid + rr * 256;          // 0..511
            int row = cidx >> 2, off = (cidx & 3) * 8;
            int arow = bm + row; if (arow >= n) arow = n - 1;
            *(float4*)&As[row * LDP + off] = *(const float4*)&Af[(size_t)arow * K + k0 + off];
            int brow = bn + row;                 // always < M by grid construction
            *(float4*)&Bs[row * LDP + off] = *(const float4*)&Wt[(size_t)brow * K + k0 + off];
        }
        __syncthreads();
        half8 af[4], bf[4];
#pragma unroll
        for (int i = 0; i < 4; i++) af[i] = *(half8*)&As[(wm * 64 + i * 16 + l16) * LDP + q * 8];
#pragma unroll
        for (int j = 0; j < 4; j++) bf[j] = *(half8*)&Bs[(wn * 64 + j * 16 + l16) * LDP + q * 8];
#pragma unroll
        for (int i = 0; i < 4; i++)
#pragma unroll
            for (int j = 0; j < 4; j++)
                acc[i][j] = __builtin_amdgcn_mfma_f32_16x16x32_f16(af[i], bf[j], acc[i][j], 0, 0, 0);
        __syncthreads();
    }
#pragma unroll
    for (int i = 0; i < 4; i++)
#pragma unroll
        for (int j = 0; j < 4; j++) {
            int col = bn + wn * 64 + j * 16 + l16;
#pragma unroll
            for (int r = 0; r < 4; r++) {
                int row = bm + wm * 64 + i * 16 + q * 4 + r;
                if (row < n) C[(size_t)row * M + col] = acc[i][j][r];
            }
        }
}

// ============================ attention ============================
__global__ __launch_bounds__(256) void attn_score_kernel(const float* __restrict__ T, const float* __restrict__ ba1,
                                                         const float* __restrict__ Wa2, const float* __restrict__ ba2,
                                                         float* __restrict__ score, int n) {
    int wave = threadIdx.x >> 6, lane = threadIdx.x & 63;
    int row = blockIdx.x * 4 + wave;
    if (row >= n) return;
    float s = 0.f;
#pragma unroll
    for (int j = lane; j < 128; j += 64) {
        float v = T[(size_t)row * 128 + j] + ba1[j];
        v = (v > 0.f) ? v : 0.01f * v;
        s += v * Wa2[j];
    }
    for (int o = 32; o > 0; o >>= 1) s += __shfl_down(s, o);
    if (lane == 0) score[row] = s + ba2[0];
}

__global__ __launch_bounds__(256) void reduce_max_kernel(const float* __restrict__ s, int n, float* __restrict__ part) {
    __shared__ float lds[256];
    float m = -3.0e38f;
    for (int i = blockIdx.x * 256 + threadIdx.x; i < n; i += gridDim.x * 256) m = fmaxf(m, s[i]);
    lds[threadIdx.x] = m; __syncthreads();
    for (int o = 128; o > 0; o >>= 1) {
        if (threadIdx.x < o) lds[threadIdx.x] = fmaxf(lds[threadIdx.x], lds[threadIdx.x + o]);
        __syncthreads();
    }
    if (threadIdx.x == 0) part[blockIdx.x] = lds[0];
}

__global__ void reduce_max_final_kernel(const float* __restrict__ part, int nb, float* __restrict__ red) {
    __shared__ float lds[256];
    float m = -3.0e38f;
    for (int i = threadIdx.x; i < nb; i += 256) m = fmaxf(m, part[i]);
    lds[threadIdx.x] = m; __syncthreads();
    for (int o = 128; o > 0; o >>= 1) {
        if (threadIdx.x < o) lds[threadIdx.x] = fmaxf(lds[threadIdx.x], lds[threadIdx.x + o]);
        __syncthreads();
    }
    if (threadIdx.x == 0) red[0] = lds[0];
}

__global__ __launch_bounds__(256) void reduce_sumexp_kernel(const float* __restrict__ s, int n,
                                                            const float* __restrict__ red, float* __restrict__ part) {
    __shared__ float lds[256];
    float mx = red[0];
    float acc = 0.f;
    for (int i = blockIdx.x * 256 + threadIdx.x; i < n; i += gridDim.x * 256) acc += expf(s[i] - mx);
    lds[threadIdx.x] = acc; __syncthreads();
    for (int o = 128; o > 0; o >>= 1) {
        if (threadIdx.x < o) lds[threadIdx.x] += lds[threadIdx.x + o];
        __syncthreads();
    }
    if (threadIdx.x == 0) part[blockIdx.x] = lds[0];
}

__global__ void reduce_sum_final_kernel(const float* __restrict__ part, int nb, float* __restrict__ red) {
    __shared__ float lds[256];
    float s = 0.f;
    for (int i = threadIdx.x; i < nb; i += 256) s += part[i];
    lds[threadIdx.x] = s; __syncthreads();
    for (int o = 128; o > 0; o >>= 1) {
        if (threadIdx.x < o) lds[threadIdx.x] += lds[threadIdx.x + o];
        __syncthreads();
    }
    if (threadIdx.x == 0) red[1] = lds[0];
}

// pooled[g,c] += striped sum of A[i,c]*exp(score[i]-mx); grid (NG, 8)
__global__ __launch_bounds__(256) void pool_kernel(const float* __restrict__ A, const float* __restrict__ score,
                                                   const int* __restrict__ offs, const int* __restrict__ cnts,
                                                   const float* __restrict__ red, float* __restrict__ pooled) {
    int g = blockIdx.x, c = threadIdx.x;
    int st = offs[g], cn = cnts[g];
    float mx = red[0];
    float acc = 0.f;
    for (int i = (int)blockIdx.y; i < cn; i += 32) {
        int i1 = i + 8, i2 = i + 16, i3 = i + 24;
        float s0 = score[st + i];
        float s1 = (i1 < cn) ? score[st + i1] : -3.0e38f;
        float s2 = (i2 < cn) ? score[st + i2] : -3.0e38f;
        float s3 = (i3 < cn) ? score[st + i3] : -3.0e38f;
        float a0 = A[(size_t)(st + i) * DIM + c];
        float a1 = (i1 < cn) ? A[(size_t)(st + i1) * DIM + c] : 0.f;
        float a2 = (i2 < cn) ? A[(size_t)(st + i2) * DIM + c] : 0.f;
        float a3 = (i3 < cn) ? A[(size_t)(st + i3) * DIM + c] : 0.f;
        acc += a0 * expf(s0 - mx) + a1 * expf(s1 - mx) + a2 * expf(s2 - mx) + a3 * expf(s3 - mx);
    }
    atomicAdd(&pooled[g * DIM + c], acc);
}

__global__ __launch_bounds__(256) void out_kernel(const float* __restrict__ pooled, const int* __restrict__ cnt,
                                                  const float* __restrict__ red, const float* __restrict__ Wo,
                                                  const float* __restrict__ bo, float* __restrict__ out) {
    __shared__ float l0[256], l1[256];
    int g = blockIdx.x, c = threadIdx.x;
    float scale = 1.f / (red[1] * fmaxf((float)cnt[g], 1.f));
    float v = pooled[g * DIM + c] * scale;
    l0[c] = v * Wo[c * 2];
    l1[c] = v * Wo[c * 2 + 1];
    __syncthreads();
    for (int o = 128; o > 0; o >>= 1) {
        if (c < o) { l0[c] += l0[c + o]; l1[c] += l1[c + o]; }
        __syncthreads();
    }
    if (c == 0) { out[g * 2] = l0[0] + bo[0]; out[g * 2 + 1] = l1[0] + bo[1]; }
}

// ============================ launch ============================
extern "C" void kernel_launch(void* const* d_in, const int* in_sizes, int n_in,
                              void* d_out, int out_size, void* d_ws, size_t ws_size,
                              hipStream_t stream) {
    const float* x       = (const float*)d_in[0];
    const int*   ei      = (const int*)d_in[1];
    const int*   batch   = (const int*)d_in[2];
    const float* bn_in_g = (const float*)d_in[3];
    const float* bn_in_b = (const float*)d_in[4];
    const float* Ws[3]   = {(const float*)d_in[5],  (const float*)d_in[9],  (const float*)d_in[13]};
    const float* bs[3]   = {(const float*)d_in[6],  (const float*)d_in[10], (const float*)d_in[14]};
    const float* gs[3]   = {(const float*)d_in[7],  (const float*)d_in[11], (const float*)d_in[15]};
    const float* bbs[3]  = {(const float*)d_in[8],  (const float*)d_in[12], (const float*)d_in[16]};
    const float* Wa1 = (const float*)d_in[17];
    const float* ba1 = (const float*)d_in[18];
    const float* Wa2 = (const float*)d_in[19];
    const float* ba2 = (const float*)d_in[20];
    const float* Wo  = (const float*)d_in[21];
    const float* bo  = (const float*)d_in[22];

    char* w = (char*)d_ws;
    size_t off = 0;
    auto alloc = [&](size_t bytes) -> void* {
        void* p = w + off;
        off += (bytes + 255) & ~(size_t)255;
        return p;
    };
    float* A    = (float*)alloc((size_t)N_NODES * DIM * 4);   // features fp32
    f16*   Afh  = (f16*)alloc((size_t)N_NODES * DIM * 2);     // features fp16 (GEMM input)
    float* B    = (float*)alloc((size_t)N_NODES * DIM * 4);   // h = xp @ W
    float* C    = (float*)alloc((size_t)N_NODES * DIM * 4);   // aggregated / attn intermediate
    f16*   Wt[3];
    for (int l = 0; l < 3; l++) Wt[l] = (f16*)alloc((size_t)DIM * DIM * 2);
    f16*   Wa1t = (f16*)alloc((size_t)128 * DIM * 2);
    int* sorted_src = (int*)alloc((size_t)N_EDGES * 4);
    int* deg    = (int*)alloc((size_t)N_NODES * 4);
    float* dinv = (float*)alloc((size_t)N_NODES * 4);
    int* rowp   = (int*)alloc((size_t)(N_NODES + 1) * 4);
    int* fill   = (int*)alloc((size_t)N_NODES * 4);
    float* score = (float*)alloc((size_t)N_NODES * 4);
    float* stats = (float*)alloc(512 * 4);
    float* mr    = (float*)alloc(512 * 4);
    int* bsums   = (int*)alloc(64 * 4);
    float* part  = (float*)alloc(256 * 4);
    float* red   = (float*)alloc(16 * 4);
    int* gstart  = (int*)alloc(64 * 4);
    int* cnt_g   = (int*)alloc(64 * 4);
    int* off_g   = (int*)alloc(64 * 4);
    float* pooled = (float*)alloc((size_t)NG * DIM * 4);

    const int* src = ei;
    const int* dst = ei + N_EDGES;

    // ---- degree + CSR (dst-sorted edges) ----
    hipMemsetAsync(deg, 0, (size_t)N_NODES * 4, stream);
    hipMemsetAsync(fill, 0, (size_t)N_NODES * 4, stream);
    count_int_kernel<<<3125, 256, 0, stream>>>(dst, N_EDGES, deg);
    dinv_kernel<<<196, 256, 0, stream>>>(deg, dinv, N_NODES);
    scan1_kernel<<<(N_NODES + SCHUNK - 1) / SCHUNK, 256, 0, stream>>>(deg, N_NODES, rowp, bsums);
    scan2_kernel<<<1, 64, 0, stream>>>(bsums, (N_NODES + SCHUNK - 1) / SCHUNK);
    scan3_kernel<<<(N_NODES + 255) / 256, 256, 0, stream>>>(rowp, bsums, N_NODES, N_EDGES);
    scatter_kernel<<<3125, 256, 0, stream>>>(src, dst, N_EDGES, rowp, fill, sorted_src);

    // ---- graph ranges from sorted batch ----
    hipMemsetAsync(gstart, 0xff, 64 * 4, stream);
    graph_bounds_kernel<<<(N_NODES + 255) / 256, 256, 0, stream>>>(batch, N_NODES, gstart);
    graph_offsets2_kernel<<<1, 64, 0, stream>>>(gstart, off_g, cnt_g);

    // ---- weight conversion (fp32 -> fp16, transposed) ----
    for (int l = 0; l < 3; l++)
        convert_wT_kernel<<<DIM * DIM / 256, 256, 0, stream>>>(Ws[l], Wt[l], DIM, DIM);
    convert_wT_kernel<<<128 * DIM / 256, 256, 0, stream>>>(Wa1, Wa1t, DIM, 128);

    // ---- input BN ----
    hipMemsetAsync(stats, 0, 512 * 4, stream);
    col_stats_kernel<<<512, 256, 0, stream>>>(x, N_NODES, stats, 0);
    finalize_stats_kernel<<<1, 256, 0, stream>>>(stats, mr, 1.f / N_NODES);
    bn_apply_kernel<<<1024, 256, 0, stream>>>(x, A, Afh, mr, bn_in_g, bn_in_b, N_NODES, 0, 0);

    // ---- GCN layers ----
    dim3 ggrid((N_NODES + BM - 1) / BM, DIM / BN);
    for (int l = 0; l < 3; l++) {
        gemm_f16_kernel<<<ggrid, 256, 0, stream>>>(Afh, Wt[l], B, N_NODES, DIM, DIM);
        gcn_agg_kernel<<<(N_NODES + 3) / 4, 256, 0, stream>>>(B, rowp, sorted_src, dinv, bs[l], C, N_NODES);
        hipMemsetAsync(stats, 0, 512 * 4, stream);
        col_stats_kernel<<<512, 256, 0, stream>>>(C, N_NODES, stats, 1);
        finalize_stats_kernel<<<1, 256, 0, stream>>>(stats, mr, 1.f / N_NODES);
        bn_apply_kernel<<<1024, 256, 0, stream>>>(C, A, Afh, mr, gs[l], bbs[l], N_NODES, 1, (l > 0) ? 1 : 0);
    }

    // ---- attention scores ----
    dim3 agrid((N_NODES + BM - 1) / BM, 1);
    gemm_f16_kernel<<<agrid, 256, 0, stream>>>(Afh, Wa1t, C, N_NODES, DIM, 128);
    attn_score_kernel<<<(N_NODES + 3) / 4, 256, 0, stream>>>(C, ba1, Wa2, ba2, score, N_NODES);
    reduce_max_kernel<<<256, 256, 0, stream>>>(score, N_NODES, part);
    reduce_max_final_kernel<<<1, 256, 0, stream>>>(part, 256, red);
    reduce_sumexp_kernel<<<256, 256, 0, stream>>>(score, N_NODES, red, part);
    reduce_sum_final_kernel<<<1, 256, 0, stream>>>(part, 256, red);

    // ---- per-graph pooling ----
    hipMemsetAsync(pooled, 0, (size_t)NG * DIM * 4, stream);
    pool_kernel<<<dim3(NG, 8), 256, 0, stream>>>(A, score, off_g, cnt_g, red, pooled);
    out_kernel<<<NG, 256, 0, stream>>>(pooled, cnt_g, red, Wo, bo, (float*)d_out);
}

// Round 4
// 831.372 us; speedup vs baseline: 2.1267x; 1.2140x over previous
//
#include <hip/hip_runtime.h>

#define N_NODES 50000
#define N_EDGES 800000
#define DIM 256
#define NG 64
#define EPS_BN 1e-5f

typedef _Float16 f16;
typedef _Float16 half8 __attribute__((ext_vector_type(8)));
typedef _Float16 half4 __attribute__((ext_vector_type(4)));
typedef float floatx4 __attribute__((ext_vector_type(4)));

// ============================ BN statistics ============================
__global__ __launch_bounds__(256) void col_stats_kernel(const float* __restrict__ X, int n,
                                                        float* __restrict__ sums, int relu) {
    int c = threadIdx.x;
    float s = 0.f, q = 0.f;
    for (int i = blockIdx.x; i < n; i += gridDim.x) {
        float v = X[(size_t)i * DIM + c];
        if (relu) v = fmaxf(v, 0.f);
        s += v; q += v * v;
    }
    atomicAdd(&sums[c], s);
    atomicAdd(&sums[DIM + c], q);
}

// input-BN stats from fp32 x
__global__ void finalize_stats_kernel(const float* __restrict__ sums, float* __restrict__ mr, float inv_n) {
    int c = threadIdx.x;
    float m = sums[c] * inv_n;
    float v = sums[DIM + c] * inv_n - m * m;
    mr[c] = m;
    mr[DIM + c] = rsqrtf(v + EPS_BN);
}

// features are fp16-only: v = bn(relu?(Cin)) (+ Af_old if residual) -> Af (f16)
__global__ __launch_bounds__(256) void bn_apply_kernel(const float* __restrict__ Cin, f16* __restrict__ Af,
                                                       const float* __restrict__ mr, const float* __restrict__ g,
                                                       const float* __restrict__ b, int n, int relu, int residual) {
    int c = threadIdx.x;
    float mean = mr[c], rstd = mr[DIM + c], gg = g[c], bb = b[c];
    for (int i = blockIdx.x; i < n; i += gridDim.x) {
        size_t idx = (size_t)i * DIM + c;
        float v = Cin[idx];
        if (relu) v = fmaxf(v, 0.f);
        v = (v - mean) * rstd * gg + bb;
        if (residual) v += (float)Af[idx];
        Af[idx] = (f16)v;
    }
}

// ============================ weight conversion: Wt[m][k] = (f16)W[k][m] ============================
__global__ void convert_wT_kernel(const float* __restrict__ W, f16* __restrict__ Wt, int K, int M) {
    int idx = blockIdx.x * 256 + threadIdx.x;
    if (idx < K * M) {
        int m = idx / K, k = idx % K;
        Wt[idx] = (f16)W[(size_t)k * M + m];
    }
}

// ============================ degree / CSR build ============================
__global__ void count_int_kernel(const int* __restrict__ idx, int n, int* __restrict__ cnt) {
    for (int i = blockIdx.x * blockDim.x + threadIdx.x; i < n; i += gridDim.x * blockDim.x)
        atomicAdd(&cnt[idx[i]], 1);
}

__global__ void dinv_kernel(const int* __restrict__ cnt, float* __restrict__ dinv, int n) {
    for (int i = blockIdx.x * blockDim.x + threadIdx.x; i < n; i += gridDim.x * blockDim.x)
        dinv[i] = rsqrtf((float)cnt[i] + 1.0f);
}

#define SCHUNK 2048
__global__ __launch_bounds__(256) void scan1_kernel(const int* __restrict__ cnt, int n,
                                                    int* __restrict__ outp, int* __restrict__ bsums) {
    __shared__ int lds[256];
    int t = threadIdx.x;
    int base = blockIdx.x * SCHUNK + t * 8;
    int v[8]; int s = 0;
#pragma unroll
    for (int j = 0; j < 8; j++) { int id = base + j; int x = (id < n) ? cnt[id] : 0; v[j] = s; s += x; }
    lds[t] = s; __syncthreads();
    for (int o = 1; o < 256; o <<= 1) {
        int add = (t >= o) ? lds[t - o] : 0;
        __syncthreads();
        lds[t] += add;
        __syncthreads();
    }
    int excl = lds[t] - s;
#pragma unroll
    for (int j = 0; j < 8; j++) { int id = base + j; if (id < n) outp[id] = excl + v[j]; }
    if (t == 255) bsums[blockIdx.x] = lds[255];
}

__global__ void scan2_kernel(int* bsums, int nb) {
    if (threadIdx.x == 0 && blockIdx.x == 0) {
        int r = 0;
        for (int i = 0; i < nb; i++) { int t = bsums[i]; bsums[i] = r; r += t; }
    }
}

__global__ void scan3_kernel(int* __restrict__ outp, const int* __restrict__ bsums, int n, int total) {
    int i = blockIdx.x * blockDim.x + threadIdx.x;
    if (i < n) outp[i] += bsums[i / SCHUNK];
    if (i == 0) outp[n] = total;
}

__global__ void scatter_kernel(const int* __restrict__ src, const int* __restrict__ dst, int ne,
                               const int* __restrict__ rowp, int* __restrict__ fill, int* __restrict__ ss) {
    for (int e = blockIdx.x * blockDim.x + threadIdx.x; e < ne; e += gridDim.x * blockDim.x) {
        int d = dst[e];
        int pos = rowp[d] + atomicAdd(&fill[d], 1);
        ss[pos] = src[e];
    }
}

// ============================ graph ranges (batch sorted -> no atomics) ============================
__global__ void graph_bounds_kernel(const int* __restrict__ batch, int n, int* __restrict__ start) {
    int i = blockIdx.x * blockDim.x + threadIdx.x;
    if (i < n) {
        int b = batch[i];
        if (i == 0 || batch[i - 1] != b) start[b] = i;
    }
}

__global__ void graph_offsets2_kernel(const int* __restrict__ start, int* __restrict__ off, int* __restrict__ cnt) {
    if (threadIdx.x == 0 && blockIdx.x == 0) {
        int nxt = N_NODES;
        for (int g = NG - 1; g >= 0; --g) {
            int s = start[g];
            int o = (s < 0) ? nxt : s;
            off[g] = o;
            cnt[g] = nxt - o;
            nxt = o;
        }
    }
}

// ============================ GCN edge aggregation (fp16 gather, fp32 accum) ============================
__global__ __launch_bounds__(256) void gcn_agg_kernel(const f16* __restrict__ h, const int* __restrict__ rowp,
                                                      const int* __restrict__ ss, const float* __restrict__ dinv,
                                                      const float* __restrict__ bias, float* __restrict__ out, int n) {
    int wave = threadIdx.x >> 6;
    int lane = threadIdx.x & 63;
    int row = blockIdx.x * 4 + wave;
    if (row >= n) return;
    int c = lane * 4;
    float ax = 0.f, ay = 0.f, az = 0.f, aw = 0.f;
    int e0 = rowp[row], e1 = rowp[row + 1];
    int e = e0;
    for (; e + 3 < e1; e += 4) {
        int s0 = ss[e], s1 = ss[e + 1], s2 = ss[e + 2], s3 = ss[e + 3];
        float w0 = dinv[s0], w1 = dinv[s1], w2 = dinv[s2], w3 = dinv[s3];
        half4 h0 = *(const half4*)&h[(size_t)s0 * DIM + c];
        half4 h1 = *(const half4*)&h[(size_t)s1 * DIM + c];
        half4 h2 = *(const half4*)&h[(size_t)s2 * DIM + c];
        half4 h3 = *(const half4*)&h[(size_t)s3 * DIM + c];
        ax += w0 * (float)h0[0] + w1 * (float)h1[0] + w2 * (float)h2[0] + w3 * (float)h3[0];
        ay += w0 * (float)h0[1] + w1 * (float)h1[1] + w2 * (float)h2[1] + w3 * (float)h3[1];
        az += w0 * (float)h0[2] + w1 * (float)h1[2] + w2 * (float)h2[2] + w3 * (float)h3[2];
        aw += w0 * (float)h0[3] + w1 * (float)h1[3] + w2 * (float)h2[3] + w3 * (float)h3[3];
    }
    for (; e < e1; e++) {
        int s = ss[e];
        float w = dinv[s];
        half4 hv = *(const half4*)&h[(size_t)s * DIM + c];
        ax += w * (float)hv[0]; ay += w * (float)hv[1]; az += w * (float)hv[2]; aw += w * (float)hv[3];
    }
    float di = dinv[row];
    float d2 = di * di;
    half4 hs = *(const half4*)&h[(size_t)row * DIM + c];
    float4 bv = *(const float4*)&bias[c];
    float4 r;
    r.x = di * ax + d2 * (float)hs[0] + bv.x;
    r.y = di * ay + d2 * (float)hs[1] + bv.y;
    r.z = di * az + d2 * (float)hs[2] + bv.z;
    r.w = di * aw + d2 * (float)hs[3] + bv.w;
    *(float4*)&out[(size_t)row * DIM + c] = r;
}

// ============================ fp16 MFMA GEMM: C[n,M] (f16) = Af[n,K] @ Wt^T ============================
#define BM 128
#define BN 128
#define BK 32
#define LDP 40
__global__ __launch_bounds__(256) void gemm_f16_kernel(const f16* __restrict__ Af, const f16* __restrict__ Wt,
                                                       f16* __restrict__ C, int n, int K, int M) {
    __shared__ __align__(16) f16 As[BM * LDP];
    __shared__ __align__(16) f16 Bs[BN * LDP];
    int tid = threadIdx.x;
    int wave = tid >> 6, lane = tid & 63;
    int wm = wave >> 1, wn = wave & 1;
    int q = lane >> 4, l16 = lane & 15;
    int bm = blockIdx.x * BM, bn = blockIdx.y * BN;
    floatx4 acc[4][4] = {};
    for (int k0 = 0; k0 < K; k0 += BK) {
#pragma unroll
        for (int rr = 0; rr < 2; rr++) {
            int cidx = tid + rr * 256;
            int row = cidx >> 2, off = (cidx & 3) * 8;
            int arow = bm + row; if (arow >= n) arow = n - 1;
            *(float4*)&As[row * LDP + off] = *(const float4*)&Af[(size_t)arow * K + k0 + off];
            int brow = bn + row;
            *(float4*)&Bs[row * LDP + off] = *(const float4*)&Wt[(size_t)brow * K + k0 + off];
        }
        __syncthreads();
        half8 af[4], bf[4];
#pragma unroll
        for (int i = 0; i < 4; i++) af[i] = *(half8*)&As[(wm * 64 + i * 16 + l16) * LDP + q * 8];
#pragma unroll
        for (int j = 0; j < 4; j++) bf[j] = *(half8*)&Bs[(wn * 64 + j * 16 + l16) * LDP + q * 8];
#pragma unroll
        for (int i = 0; i < 4; i++)
#pragma unroll
            for (int j = 0; j < 4; j++)
                acc[i][j] = __builtin_amdgcn_mfma_f32_16x16x32_f16(af[i], bf[j], acc[i][j], 0, 0, 0);
        __syncthreads();
    }
#pragma unroll
    for (int i = 0; i < 4; i++)
#pragma unroll
        for (int j = 0; j < 4; j++) {
            int col = bn + wn * 64 + j * 16 + l16;
#pragma unroll
            for (int r = 0; r < 4; r++) {
                int row = bm + wm * 64 + i * 16 + q * 4 + r;
                if (row < n) C[(size_t)row * M + col] = (f16)acc[i][j][r];
            }
        }
}

// ============================ attention ============================
__global__ __launch_bounds__(256) void attn_score_kernel(const f16* __restrict__ T, const float* __restrict__ ba1,
                                                         const float* __restrict__ Wa2, const float* __restrict__ ba2,
                                                         float* __restrict__ score, int n) {
    int wave = threadIdx.x >> 6, lane = threadIdx.x & 63;
    int row = blockIdx.x * 4 + wave;
    if (row >= n) return;
    float s = 0.f;
#pragma unroll
    for (int j = lane; j < 128; j += 64) {
        float v = (float)T[(size_t)row * 128 + j] + ba1[j];
        v = (v > 0.f) ? v : 0.01f * v;
        s += v * Wa2[j];
    }
    for (int o = 32; o > 0; o >>= 1) s += __shfl_down(s, o);
    if (lane == 0) score[row] = s + ba2[0];
}

__global__ __launch_bounds__(256) void reduce_max_kernel(const float* __restrict__ s, int n, float* __restrict__ part) {
    __shared__ float lds[256];
    float m = -3.0e38f;
    for (int i = blockIdx.x * 256 + threadIdx.x; i < n; i += gridDim.x * 256) m = fmaxf(m, s[i]);
    lds[threadIdx.x] = m; __syncthreads();
    for (int o = 128; o > 0; o >>= 1) {
        if (threadIdx.x < o) lds[threadIdx.x] = fmaxf(lds[threadIdx.x], lds[threadIdx.x + o]);
        __syncthreads();
    }
    if (threadIdx.x == 0) part[blockIdx.x] = lds[0];
}

__global__ void reduce_max_final_kernel(const float* __restrict__ part, int nb, float* __restrict__ red) {
    __shared__ float lds[256];
    float m = -3.0e38f;
    for (int i = threadIdx.x; i < nb; i += 256) m = fmaxf(m, part[i]);
    lds[threadIdx.x] = m; __syncthreads();
    for (int o = 128; o > 0; o >>= 1) {
        if (threadIdx.x < o) lds[threadIdx.x] = fmaxf(lds[threadIdx.x], lds[threadIdx.x + o]);
        __syncthreads();
    }
    if (threadIdx.x == 0) red[0] = lds[0];
}

__global__ __launch_bounds__(256) void reduce_sumexp_kernel(const float* __restrict__ s, int n,
                                                            const float* __restrict__ red, float* __restrict__ part) {
    __shared__ float lds[256];
    float mx = red[0];
    float acc = 0.f;
    for (int i = blockIdx.x * 256 + threadIdx.x; i < n; i += gridDim.x * 256) acc += expf(s[i] - mx);
    lds[threadIdx.x] = acc; __syncthreads();
    for (int o = 128; o > 0; o >>= 1) {
        if (threadIdx.x < o) lds[threadIdx.x] += lds[threadIdx.x + o];
        __syncthreads();
    }
    if (threadIdx.x == 0) part[blockIdx.x] = lds[0];
}

__global__ void reduce_sum_final_kernel(const float* __restrict__ part, int nb, float* __restrict__ red) {
    __shared__ float lds[256];
    float s = 0.f;
    for (int i = threadIdx.x; i < nb; i += 256) s += part[i];
    lds[threadIdx.x] = s; __syncthreads();
    for (int o = 128; o > 0; o >>= 1) {
        if (threadIdx.x < o) lds[threadIdx.x] += lds[threadIdx.x + o];
        __syncthreads();
    }
    if (threadIdx.x == 0) red[1] = lds[0];
}

// pooled[g,c] += striped sum of Af[i,c]*exp(score[i]-mx); grid (NG, 8)
__global__ __launch_bounds__(256) void pool_kernel(const f16* __restrict__ Af, const float* __restrict__ score,
                                                   const int* __restrict__ offs, const int* __restrict__ cnts,
                                                   const float* __restrict__ red, float* __restrict__ pooled) {
    int g = blockIdx.x, c = threadIdx.x;
    int st = offs[g], cn = cnts[g];
    float mx = red[0];
    float acc = 0.f;
    for (int i = (int)blockIdx.y; i < cn; i += 32) {
        int i1 = i + 8, i2 = i + 16, i3 = i + 24;
        float s0 = score[st + i];
        float s1 = (i1 < cn) ? score[st + i1] : -3.0e38f;
        float s2 = (i2 < cn) ? score[st + i2] : -3.0e38f;
        float s3 = (i3 < cn) ? score[st + i3] : -3.0e38f;
        float a0 = (float)Af[(size_t)(st + i) * DIM + c];
        float a1 = (i1 < cn) ? (float)Af[(size_t)(st + i1) * DIM + c] : 0.f;
        float a2 = (i2 < cn) ? (float)Af[(size_t)(st + i2) * DIM + c] : 0.f;
        float a3 = (i3 < cn) ? (float)Af[(size_t)(st + i3) * DIM + c] : 0.f;
        acc += a0 * expf(s0 - mx) + a1 * expf(s1 - mx) + a2 * expf(s2 - mx) + a3 * expf(s3 - mx);
    }
    atomicAdd(&pooled[g * DIM + c], acc);
}

__global__ __launch_bounds__(256) void out_kernel(const float* __restrict__ pooled, const int* __restrict__ cnt,
                                                  const float* __restrict__ red, const float* __restrict__ Wo,
                                                  const float* __restrict__ bo, float* __restrict__ out) {
    __shared__ float l0[256], l1[256];
    int g = blockIdx.x, c = threadIdx.x;
    float scale = 1.f / (red[1] * fmaxf((float)cnt[g], 1.f));
    float v = pooled[g * DIM + c] * scale;
    l0[c] = v * Wo[c * 2];
    l1[c] = v * Wo[c * 2 + 1];
    __syncthreads();
    for (int o = 128; o > 0; o >>= 1) {
        if (c < o) { l0[c] += l0[c + o]; l1[c] += l1[c + o]; }
        __syncthreads();
    }
    if (c == 0) { out[g * 2] = l0[0] + bo[0]; out[g * 2 + 1] = l1[0] + bo[1]; }
}

// ============================ launch ============================
extern "C" void kernel_launch(void* const* d_in, const int* in_sizes, int n_in,
                              void* d_out, int out_size, void* d_ws, size_t ws_size,
                              hipStream_t stream) {
    const float* x       = (const float*)d_in[0];
    const int*   ei      = (const int*)d_in[1];
    const int*   batch   = (const int*)d_in[2];
    const float* bn_in_g = (const float*)d_in[3];
    const float* bn_in_b = (const float*)d_in[4];
    const float* Ws[3]   = {(const float*)d_in[5],  (const float*)d_in[9],  (const float*)d_in[13]};
    const float* bs[3]   = {(const float*)d_in[6],  (const float*)d_in[10], (const float*)d_in[14]};
    const float* gs[3]   = {(const float*)d_in[7],  (const float*)d_in[11], (const float*)d_in[15]};
    const float* bbs[3]  = {(const float*)d_in[8],  (const float*)d_in[12], (const float*)d_in[16]};
    const float* Wa1 = (const float*)d_in[17];
    const float* ba1 = (const float*)d_in[18];
    const float* Wa2 = (const float*)d_in[19];
    const float* ba2 = (const float*)d_in[20];
    const float* Wo  = (const float*)d_in[21];
    const float* bo  = (const float*)d_in[22];

    char* w = (char*)d_ws;
    size_t off = 0;
    auto alloc = [&](size_t bytes) -> void* {
        void* p = w + off;
        off += (bytes + 255) & ~(size_t)255;
        return p;
    };
    f16*   Afh  = (f16*)alloc((size_t)N_NODES * DIM * 2);     // features fp16 (GEMM/pool input)
    f16*   Bh   = (f16*)alloc((size_t)N_NODES * DIM * 2);     // h = xp @ W (fp16) / attn intermediate
    float* C    = (float*)alloc((size_t)N_NODES * DIM * 4);   // aggregated (fp32, pre-BN)
    f16*   Wt[3];
    for (int l = 0; l < 3; l++) Wt[l] = (f16*)alloc((size_t)DIM * DIM * 2);
    f16*   Wa1t = (f16*)alloc((size_t)128 * DIM * 2);
    int* sorted_src = (int*)alloc((size_t)N_EDGES * 4);
    int* deg    = (int*)alloc((size_t)N_NODES * 4);
    float* dinv = (float*)alloc((size_t)N_NODES * 4);
    int* rowp   = (int*)alloc((size_t)(N_NODES + 1) * 4);
    int* fill   = (int*)alloc((size_t)N_NODES * 4);
    float* score = (float*)alloc((size_t)N_NODES * 4);
    float* stats = (float*)alloc(512 * 4);
    float* mr    = (float*)alloc(512 * 4);
    int* bsums   = (int*)alloc(64 * 4);
    float* part  = (float*)alloc(256 * 4);
    float* red   = (float*)alloc(16 * 4);
    int* gstart  = (int*)alloc(64 * 4);
    int* cnt_g   = (int*)alloc(64 * 4);
    int* off_g   = (int*)alloc(64 * 4);
    float* pooled = (float*)alloc((size_t)NG * DIM * 4);

    const int* src = ei;
    const int* dst = ei + N_EDGES;

    // ---- degree + CSR (dst-sorted edges) ----
    hipMemsetAsync(deg, 0, (size_t)N_NODES * 4, stream);
    hipMemsetAsync(fill, 0, (size_t)N_NODES * 4, stream);
    count_int_kernel<<<3125, 256, 0, stream>>>(dst, N_EDGES, deg);
    dinv_kernel<<<196, 256, 0, stream>>>(deg, dinv, N_NODES);
    scan1_kernel<<<(N_NODES + SCHUNK - 1) / SCHUNK, 256, 0, stream>>>(deg, N_NODES, rowp, bsums);
    scan2_kernel<<<1, 64, 0, stream>>>(bsums, (N_NODES + SCHUNK - 1) / SCHUNK);
    scan3_kernel<<<(N_NODES + 255) / 256, 256, 0, stream>>>(rowp, bsums, N_NODES, N_EDGES);
    scatter_kernel<<<3125, 256, 0, stream>>>(src, dst, N_EDGES, rowp, fill, sorted_src);

    // ---- graph ranges from sorted batch ----
    hipMemsetAsync(gstart, 0xff, 64 * 4, stream);
    graph_bounds_kernel<<<(N_NODES + 255) / 256, 256, 0, stream>>>(batch, N_NODES, gstart);
    graph_offsets2_kernel<<<1, 64, 0, stream>>>(gstart, off_g, cnt_g);

    // ---- weight conversion (fp32 -> fp16, transposed) ----
    for (int l = 0; l < 3; l++)
        convert_wT_kernel<<<DIM * DIM / 256, 256, 0, stream>>>(Ws[l], Wt[l], DIM, DIM);
    convert_wT_kernel<<<128 * DIM / 256, 256, 0, stream>>>(Wa1, Wa1t, DIM, 128);

    // ---- input BN ----
    hipMemsetAsync(stats, 0, 512 * 4, stream);
    col_stats_kernel<<<512, 256, 0, stream>>>(x, N_NODES, stats, 0);
    finalize_stats_kernel<<<1, 256, 0, stream>>>(stats, mr, 1.f / N_NODES);
    bn_apply_kernel<<<1024, 256, 0, stream>>>(x, Afh, mr, bn_in_g, bn_in_b, N_NODES, 0, 0);

    // ---- GCN layers ----
    dim3 ggrid((N_NODES + BM - 1) / BM, DIM / BN);
    for (int l = 0; l < 3; l++) {
        gemm_f16_kernel<<<ggrid, 256, 0, stream>>>(Afh, Wt[l], Bh, N_NODES, DIM, DIM);
        gcn_agg_kernel<<<(N_NODES + 3) / 4, 256, 0, stream>>>(Bh, rowp, sorted_src, dinv, bs[l], C, N_NODES);
        hipMemsetAsync(stats, 0, 512 * 4, stream);
        col_stats_kernel<<<512, 256, 0, stream>>>(C, N_NODES, stats, 1);
        finalize_stats_kernel<<<1, 256, 0, stream>>>(stats, mr, 1.f / N_NODES);
        bn_apply_kernel<<<1024, 256, 0, stream>>>(C, Afh, mr, gs[l], bbs[l], N_NODES, 1, (l > 0) ? 1 : 0);
    }

    // ---- attention scores ----
    dim3 agrid((N_NODES + BM - 1) / BM, 1);
    gemm_f16_kernel<<<agrid, 256, 0, stream>>>(Afh, Wa1t, Bh, N_NODES, DIM, 128);
    attn_score_kernel<<<(N_NODES + 3) / 4, 256, 0, stream>>>(Bh, ba1, Wa2, ba2, score, N_NODES);
    reduce_max_kernel<<<256, 256, 0, stream>>>(score, N_NODES, part);
    reduce_max_final_kernel<<<1, 256, 0, stream>>>(part, 256, red);
    reduce_sumexp_kernel<<<256, 256, 0, stream>>>(score, N_NODES, red, part);
    reduce_sum_final_kernel<<<1, 256, 0, stream>>>(part, 256, red);

    // ---- per-graph pooling ----
    hipMemsetAsync(pooled, 0, (size_t)NG * DIM * 4, stream);
    pool_kernel<<<dim3(NG, 8), 256, 0, stream>>>(Afh, score, off_g, cnt_g, red, pooled);
    out_kernel<<<NG, 256, 0, stream>>>(pooled, cnt_g, red, Wo, bo, (float*)d_out);
}